// Round 2
// baseline (573.213 us; speedup 1.0000x reference)
//
#include <hip/hip_runtime.h>

// TransformerBlock: B=2, S=2048, D=1024, F=4096, H=16, Dh=64, M=B*S=4096.
// Mixed precision: bf16 MFMA GEMMs + flash attention, fp32 norms/softmax/residuals.
// RoPE fused into the QKV GEMM epilogue (pair partner via __shfl_xor(v,1)).
// d_ws layout (needs ~89 MB):
//   [0,2)MB wq_b  [2,4) wk_b  [4,6) wv_b  [6,8) wo_b
//   [8,16) w1_b   [16,24) w2_b [24,32) w3_b  [32,32.5) rope cos/sin table
//   [33,49) x2 (fp32 residual)  [49,57) h/h2 (bf16)
//   [57,65) Q  [65,73) K  [73,81) V  [81,89) O      (all bf16, (B,H,S,Dh))
//   [57,89)  f1/gated (bf16 M x F)  -- reuses Q/K/V/O region after attention

typedef unsigned short u16;
typedef __attribute__((ext_vector_type(8))) short short8;   // 8 x bf16 MFMA frag
typedef __attribute__((ext_vector_type(4))) float f32x4;    // MFMA acc

#define MBYTE ((size_t)1 << 20)

typedef void __attribute__((address_space(3))) lds_void;
typedef void __attribute__((address_space(1))) glb_void;
#define GLD_LDS16(gp, lp) \
  __builtin_amdgcn_global_load_lds((glb_void*)(gp), (lds_void*)(lp), 16, 0, 0)

__device__ __forceinline__ u16 f2bf(float f) {              // RNE f32 -> bf16
  union { float f; unsigned u; } v; v.f = f;
  unsigned r = v.u + 0x7FFFu + ((v.u >> 16) & 1u);
  return (u16)(r >> 16);
}
__device__ __forceinline__ float bf2f(u16 h) {
  union { unsigned u; float f; } v; v.u = ((unsigned)h) << 16;
  return v.f;
}

// ---------------- weight convert + RoPE table ----------------
__global__ __launch_bounds__(256)
void prep_kernel(const float* __restrict__ wq, const float* __restrict__ wk,
                 const float* __restrict__ wv, const float* __restrict__ wo,
                 const float* __restrict__ w1, const float* __restrict__ w2,
                 const float* __restrict__ w3,
                 u16* wqb, u16* wkb, u16* wvb, u16* wob,
                 u16* w1b, u16* w2b, u16* w3b, float2* trig)
{
  const int y = blockIdx.y;
  if (y == 7) {                                   // cos/sin table [S=2048][32]
    const int idx = blockIdx.x * 256 + threadIdx.x;
    if (idx < 2048 * 32) {
      const int s = idx >> 5, i = idx & 31;
      const float inv = powf(10000.0f, -(float)(2 * i) / 64.0f);
      const float ang = (float)s * inv;
      trig[idx] = make_float2(cosf(ang), sinf(ang));
    }
    return;
  }
  const float* src; u16* dst; int n;
  switch (y) {
    case 0: src = wq; dst = wqb; n = 1 << 20; break;
    case 1: src = wk; dst = wkb; n = 1 << 20; break;
    case 2: src = wv; dst = wvb; n = 1 << 20; break;
    case 3: src = wo; dst = wob; n = 1 << 20; break;
    case 4: src = w1; dst = w1b; n = 1 << 22; break;
    case 5: src = w2; dst = w2b; n = 1 << 22; break;
    default: src = w3; dst = w3b; n = 1 << 22; break;
  }
  const int idx = (blockIdx.x * 256 + threadIdx.x) * 4;
  if (idx >= n) return;
  const float4 v = *(const float4*)(src + idx);
  ushort4 o; o.x = f2bf(v.x); o.y = f2bf(v.y); o.z = f2bf(v.z); o.w = f2bf(v.w);
  *(ushort4*)(dst + idx) = o;
}

// ---------------- RMSNorm: fp32 in -> bf16 out, one row per block ----------
__global__ __launch_bounds__(256)
void rmsnorm_kernel(const float* __restrict__ x, const float* __restrict__ g,
                    u16* __restrict__ out)
{
  __shared__ float red[4];
  const int row = blockIdx.x, tid = threadIdx.x;
  const float4 v = ((const float4*)(x + (size_t)row * 1024))[tid];
  float ss = v.x * v.x + v.y * v.y + v.z * v.z + v.w * v.w;
  #pragma unroll
  for (int off = 32; off >= 1; off >>= 1) ss += __shfl_xor(ss, off, 64);
  if ((tid & 63) == 0) red[tid >> 6] = ss;
  __syncthreads();
  const float tot = red[0] + red[1] + red[2] + red[3];
  const float rs = rsqrtf(tot * (1.0f / 1024.0f) + 1e-5f);
  const float4 gg = ((const float4*)g)[tid];
  ushort4 o;
  o.x = f2bf(v.x * rs * gg.x); o.y = f2bf(v.y * rs * gg.y);
  o.z = f2bf(v.z * rs * gg.z); o.w = f2bf(v.w * rs * gg.w);
  ((ushort4*)(out + (size_t)row * 1024))[tid] = o;
}

// ---------------- GEMM core (m97 structure): C = A(MxK) * W(NxK)^T ---------
// BK=32, 4 waves. Wave grid WRN x WCN. LDS staged with global_load_lds x16.
template<int TM, int TN, int WRN, int WCN>
__device__ __forceinline__ void gemm_core(const u16* __restrict__ A,
                                          const u16* __restrict__ Bw,
                                          int K, int bm, int bn,
                                          u16* As, u16* Bs,
                                          f32x4 (&acc)[TM / (16 * WRN)][TN / (16 * WCN)])
{
  constexpr int MT = TM / (16 * WRN), NT = TN / (16 * WCN);
  constexpr int CA = TM / 16, CB = TN / 16;    // 1KB staging chunks
  const int tid = threadIdx.x, wid = tid >> 6, lane = tid & 63;
  const int wr = wid / WCN, wc = wid % WCN;
  const int lr = lane & 15, lg = lane >> 4;
  const int srow = lane >> 2;                  // row within 16-row chunk
  const int skel = (lane & 3) * 8;             // k-element offset (8 bf16 = 16B)
  const size_t aRow0 = (size_t)bm * TM;
  const size_t bRow0 = (size_t)bn * TN;

  for (int k0 = 0; k0 < K; k0 += 32) {
    #pragma unroll
    for (int i = 0; i < CA / 4; i++) {
      int c = wid + i * 4;
      GLD_LDS16(A + (aRow0 + c * 16 + srow) * K + k0 + skel, As + c * 512);
    }
    #pragma unroll
    for (int i = 0; i < CB / 4; i++) {
      int c = wid + i * 4;
      GLD_LDS16(Bw + (bRow0 + c * 16 + srow) * K + k0 + skel, Bs + c * 512);
    }
    __syncthreads();
    short8 af[MT], bfr[NT];
    #pragma unroll
    for (int mt = 0; mt < MT; mt++)
      af[mt] = *(const short8*)&As[(wr * (MT * 16) + mt * 16 + lr) * 32 + lg * 8];
    #pragma unroll
    for (int nt = 0; nt < NT; nt++)
      bfr[nt] = *(const short8*)&Bs[(wc * (NT * 16) + nt * 16 + lr) * 32 + lg * 8];
    #pragma unroll
    for (int mt = 0; mt < MT; mt++)
      #pragma unroll
      for (int nt = 0; nt < NT; nt++)
        acc[mt][nt] = __builtin_amdgcn_mfma_f32_16x16x32_bf16(af[mt], bfr[nt],
                                                              acc[mt][nt], 0, 0, 0);
    __syncthreads();
  }
}

// ---- QKV GEMM: z picks weight; RoPE fused in epilogue; (B,H,S,Dh) store ----
__global__ __launch_bounds__(256)
void gemm_qkv(const u16* __restrict__ A,
              const u16* __restrict__ wqb, const u16* __restrict__ wkb,
              const u16* __restrict__ wvb,
              u16* Qb, u16* Kb, u16* Vb, const float2* __restrict__ trig)
{
  __shared__ u16 As[128 * 32];
  __shared__ u16 Bs[128 * 32];
  const u16* Bw = blockIdx.z == 0 ? wqb : (blockIdx.z == 1 ? wkb : wvb);
  u16* out = blockIdx.z == 0 ? Qb : (blockIdx.z == 1 ? Kb : Vb);
  const bool isQK = blockIdx.z < 2;
  f32x4 acc[4][4];
  const f32x4 zero = {0.f, 0.f, 0.f, 0.f};
  #pragma unroll
  for (int i = 0; i < 4; i++)
    #pragma unroll
    for (int j = 0; j < 4; j++) acc[i][j] = zero;
  gemm_core<128, 128, 2, 2>(A, Bw, 1024, blockIdx.y, blockIdx.x, As, Bs, acc);
  const int lane = threadIdx.x & 63, wid = threadIdx.x >> 6;
  const int wr = wid >> 1, wc = wid & 1, lr = lane & 15, lg = lane >> 4;
  #pragma unroll
  for (int mt = 0; mt < 4; mt++)
    #pragma unroll
    for (int nt = 0; nt < 4; nt++)
      #pragma unroll
      for (int j = 0; j < 4; j++) {
        int row = blockIdx.y * 128 + wr * 64 + mt * 16 + lg * 4 + j;  // m = b*2048+s
        int col = blockIdx.x * 128 + wc * 64 + nt * 16 + lr;          // n = h*64+d
        int b = row >> 11, s = row & 2047, hh = col >> 6, d = col & 63;
        float v = acc[mt][nt][j];
        if (isQK) {
          // RoPE pair (2i,2i+1) sits on lanes lr, lr^1 (same lg) of this tile.
          float p = __shfl_xor(v, 1);
          const float2 cs = trig[s * 32 + (d >> 1)];
          v = ((d & 1) == 0) ? (v * cs.x - p * cs.y)   // r1 = x1*cos - x2*sin
                             : (p * cs.y + v * cs.x);  // r2 = x1*sin + x2*cos
        }
        out[(((size_t)(b * 16 + hh)) * 2048 + s) * 64 + d] = f2bf(v);
      }
}

// ---------------- generic GEMM with epilogue variants -----------------------
// EP: 1 = bf16 store; 2 = fp32 store of res+acc; 3 = silu(gatein)*acc -> bf16
template<int EP, int TM, int TN, int WRN, int WCN>
__global__ __launch_bounds__(256)
void gemm_one(const u16* __restrict__ A, const u16* __restrict__ Bw, int K, int N,
              u16* outb, float* outf, const float* res, const u16* gatein)
{
  __shared__ u16 As[TM * 32];
  __shared__ u16 Bs[TN * 32];
  constexpr int MT = TM / (16 * WRN), NT = TN / (16 * WCN);
  f32x4 acc[MT][NT];
  const f32x4 zero = {0.f, 0.f, 0.f, 0.f};
  #pragma unroll
  for (int i = 0; i < MT; i++)
    #pragma unroll
    for (int j = 0; j < NT; j++) acc[i][j] = zero;
  gemm_core<TM, TN, WRN, WCN>(A, Bw, K, blockIdx.y, blockIdx.x, As, Bs, acc);
  const int lane = threadIdx.x & 63, wid = threadIdx.x >> 6;
  const int wr = wid / WCN, wc = wid % WCN, lr = lane & 15, lg = lane >> 4;
  #pragma unroll
  for (int mt = 0; mt < MT; mt++)
    #pragma unroll
    for (int nt = 0; nt < NT; nt++)
      #pragma unroll
      for (int j = 0; j < 4; j++) {
        int row = blockIdx.y * TM + wr * (MT * 16) + mt * 16 + lg * 4 + j;
        int col = blockIdx.x * TN + wc * (NT * 16) + nt * 16 + lr;
        size_t o = (size_t)row * N + col;
        float v = acc[mt][nt][j];
        if constexpr (EP == 1) {
          outb[o] = f2bf(v);
        } else if constexpr (EP == 2) {
          outf[o] = res[o] + v;
        } else {
          float a1 = bf2f(gatein[o]);
          float sg = a1 / (1.0f + __expf(-a1));
          outb[o] = f2bf(sg * v);
        }
      }
}

// ---------------- causal flash attention ------------------------------------
// grid (S/64, B*H), 4 waves; wave owns 16 q rows. KBLK=64, Dh=64.
// K tile: linear LDS via global_load_lds, chunk-XOR-swizzled source (G4/#21).
// V tile: reg-staged + transposed+swizzled ds_write -> Vt[dim][key].
// P round-trips via per-wave padded LDS ([16][72]) to re-layout C->A frags.
__global__ __launch_bounds__(256)
void flash_attn(const u16* __restrict__ Qb, const u16* __restrict__ Kb,
                const u16* __restrict__ Vb, u16* __restrict__ Ob)
{
  __shared__ u16 Ks[64 * 64];
  __shared__ u16 Vt[64 * 64];
  __shared__ u16 Ps[4 * 16 * 72];
  const int tid = threadIdx.x, wid = tid >> 6, lane = tid & 63;
  const int lr = lane & 15, lg = lane >> 4;
  const int qt = blockIdx.x, bh = blockIdx.y;
  const size_t base = (size_t)bh * (2048 * 64);

  short8 qf[2];
  #pragma unroll
  for (int kc = 0; kc < 2; kc++)
    qf[kc] = *(const short8*)&Qb[base + (size_t)(qt * 64 + wid * 16 + lr) * 64
                                 + kc * 32 + lg * 8];

  f32x4 oacc[4];
  float mrow[4], lrow[4];
  const f32x4 zero = {0.f, 0.f, 0.f, 0.f};
  #pragma unroll
  for (int d = 0; d < 4; d++) oacc[d] = zero;
  #pragma unroll
  for (int j = 0; j < 4; j++) { mrow[j] = -1e30f; lrow[j] = 0.0f; }

  for (int kt = 0; kt <= qt; kt++) {
    // stage K (swizzled source -> linear LDS; read side applies same XOR)
    #pragma unroll
    for (int c = 0; c < 2; c++) {
      int ci = (wid * 2 + c) * 64 + lane;       // 16B chunk id 0..511
      int row = ci >> 3;                         // key row (128B rows)
      int lch = (ci & 7) ^ (row & 7);            // logical dim-chunk
      GLD_LDS16(Kb + base + (size_t)(kt * 64 + row) * 64 + lch * 8,
                (u16*)Ks + (wid * 2 + c) * 512);
    }
    // stage V transposed: Vt[dim][key], chunk XOR (key>>3)^(dim&7)
    #pragma unroll
    for (int c = 0; c < 2; c++) {
      int key = lane;
      int dc = c * 4 + wid;                      // dim chunk 0..7
      short8 vv = *(const short8*)&Vb[base + (size_t)(kt * 64 + key) * 64 + dc * 8];
      #pragma unroll
      for (int j = 0; j < 8; j++) {
        int d = dc * 8 + j;
        int byt = d * 128 + (((key >> 3) ^ (d & 7)) << 4) + ((key & 7) << 1);
        *(u16*)((char*)Vt + byt) = (u16)vv[j];
      }
    }
    __syncthreads();

    // S = (Q K^T) * 1/8, causal mask on diagonal tile
    f32x4 sv[4];
    #pragma unroll
    for (int nt = 0; nt < 4; nt++) {
      f32x4 s = zero;
      #pragma unroll
      for (int kc = 0; kc < 2; kc++) {
        int row = nt * 16 + lr;
        int pch = (kc * 4 + lg) ^ (row & 7);
        short8 kf = *(const short8*)((const char*)Ks + row * 128 + pch * 16);
        s = __builtin_amdgcn_mfma_f32_16x16x32_bf16(qf[kc], kf, s, 0, 0, 0);
      }
      s *= 0.125f;
      if (kt == qt) {
        int key = kt * 64 + nt * 16 + lr;
        #pragma unroll
        for (int j = 0; j < 4; j++) {
          int q = qt * 64 + wid * 16 + lg * 4 + j;
          if (key > q) s[j] = -1e30f;
        }
      }
      sv[nt] = s;
    }

    // online softmax, rows r = lg*4+j, reduce across 16 lanes of the group
    #pragma unroll
    for (int j = 0; j < 4; j++) {
      float tm = fmaxf(fmaxf(sv[0][j], sv[1][j]), fmaxf(sv[2][j], sv[3][j]));
      #pragma unroll
      for (int off = 8; off >= 1; off >>= 1) tm = fmaxf(tm, __shfl_xor(tm, off, 64));
      float mnew = fmaxf(mrow[j], tm);
      float esc = __expf(mrow[j] - mnew);
      mrow[j] = mnew;
      float rs = 0.f;
      #pragma unroll
      for (int nt = 0; nt < 4; nt++) {
        float p = __expf(sv[nt][j] - mnew);
        sv[nt][j] = p;
        rs += p;
      }
      #pragma unroll
      for (int off = 8; off >= 1; off >>= 1) rs += __shfl_xor(rs, off, 64);
      lrow[j] = lrow[j] * esc + rs;
      #pragma unroll
      for (int dt = 0; dt < 4; dt++) oacc[dt][j] *= esc;
    }

    // P (C layout) -> per-wave LDS -> A frags
    u16* myP = (u16*)Ps + wid * (16 * 72);
    #pragma unroll
    for (int nt = 0; nt < 4; nt++)
      #pragma unroll
      for (int j = 0; j < 4; j++)
        myP[(lg * 4 + j) * 72 + nt * 16 + lr] = f2bf(sv[nt][j]);
    asm volatile("s_waitcnt lgkmcnt(0)" ::: "memory");
    short8 pa[2];
    #pragma unroll
    for (int kc = 0; kc < 2; kc++)
      pa[kc] = *(const short8*)&myP[lr * 72 + kc * 32 + lg * 8];

    // O += P V
    #pragma unroll
    for (int dt = 0; dt < 4; dt++) {
      #pragma unroll
      for (int kc = 0; kc < 2; kc++) {
        int d = dt * 16 + lr;
        int pch = (kc * 4 + lg) ^ (d & 7);
        short8 vf = *(const short8*)((const char*)Vt + d * 128 + pch * 16);
        oacc[dt] = __builtin_amdgcn_mfma_f32_16x16x32_bf16(pa[kc], vf, oacc[dt], 0, 0, 0);
      }
    }
    __syncthreads();
  }

  // write O as (B,S,D) bf16
  const int b = bh >> 4, h = bh & 15;
  #pragma unroll
  for (int dt = 0; dt < 4; dt++)
    #pragma unroll
    for (int j = 0; j < 4; j++) {
      int sq = qt * 64 + wid * 16 + lg * 4 + j;
      Ob[((size_t)(b * 2048 + sq)) * 1024 + h * 64 + dt * 16 + lr] =
          f2bf(oacc[dt][j] / lrow[j]);
    }
}

// ---------------- launch ----------------------------------------------------
extern "C" void kernel_launch(void* const* d_in, const int* in_sizes, int n_in,
                              void* d_out, int out_size, void* d_ws, size_t ws_size,
                              hipStream_t stream)
{
  const float* x  = (const float*)d_in[0];
  const float* wq = (const float*)d_in[1];
  const float* wk = (const float*)d_in[2];
  const float* wv = (const float*)d_in[3];
  const float* wo = (const float*)d_in[4];
  const float* w1 = (const float*)d_in[5];
  const float* w2 = (const float*)d_in[6];
  const float* w3 = (const float*)d_in[7];
  const float* g1 = (const float*)d_in[8];
  const float* g2 = (const float*)d_in[9];
  float* out = (float*)d_out;
  char* ws = (char*)d_ws;

  u16*    wqb  = (u16*)   (ws + 0 * MBYTE);
  u16*    wkb  = (u16*)   (ws + 2 * MBYTE);
  u16*    wvb  = (u16*)   (ws + 4 * MBYTE);
  u16*    wob  = (u16*)   (ws + 6 * MBYTE);
  u16*    w1b  = (u16*)   (ws + 8 * MBYTE);
  u16*    w2b  = (u16*)   (ws + 16 * MBYTE);
  u16*    w3b  = (u16*)   (ws + 24 * MBYTE);
  float2* trig = (float2*)(ws + 32 * MBYTE);
  float*  x2   = (float*) (ws + 33 * MBYTE);
  u16*    hb   = (u16*)   (ws + 49 * MBYTE);
  u16*    Qb   = (u16*)   (ws + 57 * MBYTE);
  u16*    Kb   = (u16*)   (ws + 65 * MBYTE);
  u16*    Vb   = (u16*)   (ws + 73 * MBYTE);
  u16*    Ob   = (u16*)   (ws + 81 * MBYTE);
  u16*    f1   = (u16*)   (ws + 57 * MBYTE);   // reuse Q..O after attention

  prep_kernel<<<dim3(4096, 8), 256, 0, stream>>>(wq, wk, wv, wo, w1, w2, w3,
                                                 wqb, wkb, wvb, wob, w1b, w2b, w3b,
                                                 trig);
  rmsnorm_kernel<<<4096, 256, 0, stream>>>(x, g1, hb);
  gemm_qkv<<<dim3(8, 32, 3), 256, 0, stream>>>(hb, wqb, wkb, wvb, Qb, Kb, Vb, trig);
  flash_attn<<<dim3(32, 32), 256, 0, stream>>>(Qb, Kb, Vb, Ob);
  gemm_one<2, 64, 128, 1, 4><<<dim3(8, 64), 256, 0, stream>>>(
      Ob, wob, 1024, 1024, nullptr, x2, x, nullptr);
  rmsnorm_kernel<<<4096, 256, 0, stream>>>(x2, g2, hb);
  gemm_one<1, 128, 128, 2, 2><<<dim3(32, 32), 256, 0, stream>>>(
      hb, w1b, 1024, 4096, f1, nullptr, nullptr, nullptr);
  gemm_one<3, 128, 128, 2, 2><<<dim3(32, 32), 256, 0, stream>>>(
      hb, w3b, 1024, 4096, f1, nullptr, nullptr, f1);
  gemm_one<2, 64, 128, 1, 4><<<dim3(8, 64), 256, 0, stream>>>(
      f1, w2b, 4096, 1024, nullptr, out, x2, nullptr);
}

// Round 9
// 497.786 us; speedup vs baseline: 1.1515x; 1.1515x over previous
//
#include <hip/hip_runtime.h>

// TransformerBlock: B=2, S=2048, D=1024, F=4096, H=16, Dh=64, M=B*S=4096.
// Mixed precision: bf16 MFMA GEMMs + flash attention, fp32 norms/softmax/residuals.
// R3: flash_attn qt<->CU de-alias + double-buffered prefetch; w1+w3 fused.

typedef unsigned short u16;
typedef __attribute__((ext_vector_type(8))) short short8;   // 8 x bf16 MFMA frag
typedef __attribute__((ext_vector_type(4))) float f32x4;    // MFMA acc

#define MBYTE ((size_t)1 << 20)

typedef void __attribute__((address_space(3))) lds_void;
typedef void __attribute__((address_space(1))) glb_void;
#define GLD_LDS16(gp, lp) \
  __builtin_amdgcn_global_load_lds((glb_void*)(gp), (lds_void*)(lp), 16, 0, 0)

__device__ __forceinline__ u16 f2bf(float f) {              // RNE f32 -> bf16
  union { float f; unsigned u; } v; v.f = f;
  unsigned r = v.u + 0x7FFFu + ((v.u >> 16) & 1u);
  return (u16)(r >> 16);
}
__device__ __forceinline__ float bf2f(u16 h) {
  union { unsigned u; float f; } v; v.u = ((unsigned)h) << 16;
  return v.f;
}

// ---------------- weight convert + RoPE table ----------------
__global__ __launch_bounds__(256)
void prep_kernel(const float* __restrict__ wq, const float* __restrict__ wk,
                 const float* __restrict__ wv, const float* __restrict__ wo,
                 const float* __restrict__ w1, const float* __restrict__ w2,
                 const float* __restrict__ w3,
                 u16* wqb, u16* wkb, u16* wvb, u16* wob,
                 u16* w1b, u16* w2b, u16* w3b, float2* trig)
{
  const int y = blockIdx.y;
  if (y == 7) {                                   // cos/sin table [S=2048][32]
    const int idx = blockIdx.x * 256 + threadIdx.x;
    if (idx < 2048 * 32) {
      const int s = idx >> 5, i = idx & 31;
      const float inv = powf(10000.0f, -(float)(2 * i) / 64.0f);
      const float ang = (float)s * inv;
      trig[idx] = make_float2(cosf(ang), sinf(ang));
    }
    return;
  }
  const float* src; u16* dst; int n;
  switch (y) {
    case 0: src = wq; dst = wqb; n = 1 << 20; break;
    case 1: src = wk; dst = wkb; n = 1 << 20; break;
    case 2: src = wv; dst = wvb; n = 1 << 20; break;
    case 3: src = wo; dst = wob; n = 1 << 20; break;
    case 4: src = w1; dst = w1b; n = 1 << 22; break;
    case 5: src = w2; dst = w2b; n = 1 << 22; break;
    default: src = w3; dst = w3b; n = 1 << 22; break;
  }
  const int idx = (blockIdx.x * 256 + threadIdx.x) * 4;
  if (idx >= n) return;
  const float4 v = *(const float4*)(src + idx);
  ushort4 o; o.x = f2bf(v.x); o.y = f2bf(v.y); o.z = f2bf(v.z); o.w = f2bf(v.w);
  *(ushort4*)(dst + idx) = o;
}

// ---------------- RMSNorm: fp32 in -> bf16 out, one row per block ----------
__global__ __launch_bounds__(256)
void rmsnorm_kernel(const float* __restrict__ x, const float* __restrict__ g,
                    u16* __restrict__ out)
{
  __shared__ float red[4];
  const int row = blockIdx.x, tid = threadIdx.x;
  const float4 v = ((const float4*)(x + (size_t)row * 1024))[tid];
  float ss = v.x * v.x + v.y * v.y + v.z * v.z + v.w * v.w;
  #pragma unroll
  for (int off = 32; off >= 1; off >>= 1) ss += __shfl_xor(ss, off, 64);
  if ((tid & 63) == 0) red[tid >> 6] = ss;
  __syncthreads();
  const float tot = red[0] + red[1] + red[2] + red[3];
  const float rs = rsqrtf(tot * (1.0f / 1024.0f) + 1e-5f);
  const float4 gg = ((const float4*)g)[tid];
  ushort4 o;
  o.x = f2bf(v.x * rs * gg.x); o.y = f2bf(v.y * rs * gg.y);
  o.z = f2bf(v.z * rs * gg.z); o.w = f2bf(v.w * rs * gg.w);
  ((ushort4*)(out + (size_t)row * 1024))[tid] = o;
}

// ---------------- GEMM core (m97 structure): C = A(MxK) * W(NxK)^T ---------
template<int TM, int TN, int WRN, int WCN>
__device__ __forceinline__ void gemm_core(const u16* __restrict__ A,
                                          const u16* __restrict__ Bw,
                                          int K, int bm, int bn,
                                          u16* As, u16* Bs,
                                          f32x4 (&acc)[TM / (16 * WRN)][TN / (16 * WCN)])
{
  constexpr int MT = TM / (16 * WRN), NT = TN / (16 * WCN);
  constexpr int CA = TM / 16, CB = TN / 16;    // 1KB staging chunks
  const int tid = threadIdx.x, wid = tid >> 6, lane = tid & 63;
  const int wr = wid / WCN, wc = wid % WCN;
  const int lr = lane & 15, lg = lane >> 4;
  const int srow = lane >> 2;                  // row within 16-row chunk
  const int skel = (lane & 3) * 8;             // k-element offset (8 bf16 = 16B)
  const size_t aRow0 = (size_t)bm * TM;
  const size_t bRow0 = (size_t)bn * TN;

  for (int k0 = 0; k0 < K; k0 += 32) {
    #pragma unroll
    for (int i = 0; i < CA / 4; i++) {
      int c = wid + i * 4;
      GLD_LDS16(A + (aRow0 + c * 16 + srow) * K + k0 + skel, As + c * 512);
    }
    #pragma unroll
    for (int i = 0; i < CB / 4; i++) {
      int c = wid + i * 4;
      GLD_LDS16(Bw + (bRow0 + c * 16 + srow) * K + k0 + skel, Bs + c * 512);
    }
    __syncthreads();
    short8 af[MT], bfr[NT];
    #pragma unroll
    for (int mt = 0; mt < MT; mt++)
      af[mt] = *(const short8*)&As[(wr * (MT * 16) + mt * 16 + lr) * 32 + lg * 8];
    #pragma unroll
    for (int nt = 0; nt < NT; nt++)
      bfr[nt] = *(const short8*)&Bs[(wc * (NT * 16) + nt * 16 + lr) * 32 + lg * 8];
    #pragma unroll
    for (int mt = 0; mt < MT; mt++)
      #pragma unroll
      for (int nt = 0; nt < NT; nt++)
        acc[mt][nt] = __builtin_amdgcn_mfma_f32_16x16x32_bf16(af[mt], bfr[nt],
                                                              acc[mt][nt], 0, 0, 0);
    __syncthreads();
  }
}

// ---- QKV GEMM: z picks weight; RoPE fused in epilogue; (B,H,S,Dh) store ----
__global__ __launch_bounds__(256)
void gemm_qkv(const u16* __restrict__ A,
              const u16* __restrict__ wqb, const u16* __restrict__ wkb,
              const u16* __restrict__ wvb,
              u16* Qb, u16* Kb, u16* Vb, const float2* __restrict__ trig)
{
  __shared__ u16 As[128 * 32];
  __shared__ u16 Bs[128 * 32];
  const u16* Bw = blockIdx.z == 0 ? wqb : (blockIdx.z == 1 ? wkb : wvb);
  u16* out = blockIdx.z == 0 ? Qb : (blockIdx.z == 1 ? Kb : Vb);
  const bool isQK = blockIdx.z < 2;
  f32x4 acc[4][4];
  const f32x4 zero = {0.f, 0.f, 0.f, 0.f};
  #pragma unroll
  for (int i = 0; i < 4; i++)
    #pragma unroll
    for (int j = 0; j < 4; j++) acc[i][j] = zero;
  gemm_core<128, 128, 2, 2>(A, Bw, 1024, blockIdx.y, blockIdx.x, As, Bs, acc);
  const int lane = threadIdx.x & 63, wid = threadIdx.x >> 6;
  const int wr = wid >> 1, wc = wid & 1, lr = lane & 15, lg = lane >> 4;
  #pragma unroll
  for (int mt = 0; mt < 4; mt++)
    #pragma unroll
    for (int nt = 0; nt < 4; nt++)
      #pragma unroll
      for (int j = 0; j < 4; j++) {
        int row = blockIdx.y * 128 + wr * 64 + mt * 16 + lg * 4 + j;  // m = b*2048+s
        int col = blockIdx.x * 128 + wc * 64 + nt * 16 + lr;          // n = h*64+d
        int b = row >> 11, s = row & 2047, hh = col >> 6, d = col & 63;
        float v = acc[mt][nt][j];
        if (isQK) {
          // RoPE pair (2i,2i+1) sits on lanes lr, lr^1 (same lg) of this tile.
          float p = __shfl_xor(v, 1);
          const float2 cs = trig[s * 32 + (d >> 1)];
          v = ((d & 1) == 0) ? (v * cs.x - p * cs.y)   // r1 = x1*cos - x2*sin
                             : (p * cs.y + v * cs.x);  // r2 = x1*sin + x2*cos
        }
        out[(((size_t)(b * 16 + hh)) * 2048 + s) * 64 + d] = f2bf(v);
      }
}

// ---------------- generic GEMM with epilogue variants -----------------------
// EP: 1 = bf16 store; 2 = fp32 store of res+acc
template<int EP, int TM, int TN, int WRN, int WCN>
__global__ __launch_bounds__(256)
void gemm_one(const u16* __restrict__ A, const u16* __restrict__ Bw, int K, int N,
              u16* outb, float* outf, const float* res)
{
  __shared__ u16 As[TM * 32];
  __shared__ u16 Bs[TN * 32];
  constexpr int MT = TM / (16 * WRN), NT = TN / (16 * WCN);
  f32x4 acc[MT][NT];
  const f32x4 zero = {0.f, 0.f, 0.f, 0.f};
  #pragma unroll
  for (int i = 0; i < MT; i++)
    #pragma unroll
    for (int j = 0; j < NT; j++) acc[i][j] = zero;
  gemm_core<TM, TN, WRN, WCN>(A, Bw, K, blockIdx.y, blockIdx.x, As, Bs, acc);
  const int lane = threadIdx.x & 63, wid = threadIdx.x >> 6;
  const int wr = wid / WCN, wc = wid % WCN, lr = lane & 15, lg = lane >> 4;
  #pragma unroll
  for (int mt = 0; mt < MT; mt++)
    #pragma unroll
    for (int nt = 0; nt < NT; nt++)
      #pragma unroll
      for (int j = 0; j < 4; j++) {
        int row = blockIdx.y * TM + wr * (MT * 16) + mt * 16 + lg * 4 + j;
        int col = blockIdx.x * TN + wc * (NT * 16) + nt * 16 + lr;
        size_t o = (size_t)row * N + col;
        float v = acc[mt][nt][j];
        if constexpr (EP == 1) {
          outb[o] = f2bf(v);
        } else {
          outf[o] = res[o] + v;
        }
      }
}

// ---- fused FFN up: f1 = silu(h w1^T) * (h w3^T), bf16 out ------------------
// TM=128, TN=64, 4 waves (2x2), A staged once for both weights.
__global__ __launch_bounds__(256)
void gemm_ffn13(const u16* __restrict__ A, const u16* __restrict__ W1,
                const u16* __restrict__ W3, u16* __restrict__ outb)
{
  __shared__ u16 As[128 * 32];
  __shared__ u16 B1s[64 * 32];
  __shared__ u16 B3s[64 * 32];
  f32x4 acc1[4][2], acc3[4][2];
  const f32x4 zero = {0.f, 0.f, 0.f, 0.f};
  #pragma unroll
  for (int i = 0; i < 4; i++)
    #pragma unroll
    for (int j = 0; j < 2; j++) { acc1[i][j] = zero; acc3[i][j] = zero; }
  const int tid = threadIdx.x, wid = tid >> 6, lane = tid & 63;
  const int wr = wid >> 1, wc = wid & 1;
  const int lr = lane & 15, lg = lane >> 4;
  const int srow = lane >> 2;
  const int skel = (lane & 3) * 8;
  const size_t aRow0 = (size_t)blockIdx.y * 128;
  const size_t bRow0 = (size_t)blockIdx.x * 64;

  for (int k0 = 0; k0 < 1024; k0 += 32) {
    #pragma unroll
    for (int i = 0; i < 2; i++) {
      int c = wid + i * 4;
      GLD_LDS16(A + (aRow0 + c * 16 + srow) * 1024 + k0 + skel, As + c * 512);
    }
    GLD_LDS16(W1 + (bRow0 + wid * 16 + srow) * 1024 + k0 + skel, B1s + wid * 512);
    GLD_LDS16(W3 + (bRow0 + wid * 16 + srow) * 1024 + k0 + skel, B3s + wid * 512);
    __syncthreads();
    short8 af[4], b1[2], b3[2];
    #pragma unroll
    for (int mt = 0; mt < 4; mt++)
      af[mt] = *(const short8*)&As[(wr * 64 + mt * 16 + lr) * 32 + lg * 8];
    #pragma unroll
    for (int nt = 0; nt < 2; nt++) {
      b1[nt] = *(const short8*)&B1s[(wc * 32 + nt * 16 + lr) * 32 + lg * 8];
      b3[nt] = *(const short8*)&B3s[(wc * 32 + nt * 16 + lr) * 32 + lg * 8];
    }
    #pragma unroll
    for (int mt = 0; mt < 4; mt++)
      #pragma unroll
      for (int nt = 0; nt < 2; nt++) {
        acc1[mt][nt] = __builtin_amdgcn_mfma_f32_16x16x32_bf16(af[mt], b1[nt],
                                                               acc1[mt][nt], 0, 0, 0);
        acc3[mt][nt] = __builtin_amdgcn_mfma_f32_16x16x32_bf16(af[mt], b3[nt],
                                                               acc3[mt][nt], 0, 0, 0);
      }
    __syncthreads();
  }
  #pragma unroll
  for (int mt = 0; mt < 4; mt++)
    #pragma unroll
    for (int nt = 0; nt < 2; nt++)
      #pragma unroll
      for (int j = 0; j < 4; j++) {
        int row = blockIdx.y * 128 + wr * 64 + mt * 16 + lg * 4 + j;
        int col = blockIdx.x * 64 + wc * 32 + nt * 16 + lr;
        float v1 = acc1[mt][nt][j], v3 = acc3[mt][nt][j];
        float sg = v1 / (1.0f + __expf(-v1));
        outb[(size_t)row * 4096 + col] = f2bf(sg * v3);
      }
}

// ---------------- causal flash attention (v2) -------------------------------
// grid (32, 32): qt = (x+y)&31 de-aliases qt from CU id (balance);
// double-buffered K/V with async prefetch (issue-early / write-late).
__global__ __launch_bounds__(256)
void flash_attn(const u16* __restrict__ Qb, const u16* __restrict__ Kb,
                const u16* __restrict__ Vb, u16* __restrict__ Ob)
{
  __shared__ u16 Ks[2][64 * 64];
  __shared__ u16 Vt[2][64 * 64];
  __shared__ u16 Ps[4 * 16 * 72];
  const int tid = threadIdx.x, wid = tid >> 6, lane = tid & 63;
  const int lr = lane & 15, lg = lane >> 4;
  const int bh = blockIdx.y;
  const int qt = (blockIdx.x + blockIdx.y) & 31;   // de-alias qt from CU id
  const size_t base = (size_t)bh * (2048 * 64);

  short8 qf[2];
  #pragma unroll
  for (int kc = 0; kc < 2; kc++)
    qf[kc] = *(const short8*)&Qb[base + (size_t)(qt * 64 + wid * 16 + lr) * 64
                                 + kc * 32 + lg * 8];

  f32x4 oacc[4];
  float mrow[4], lrow[4];
  const f32x4 zero = {0.f, 0.f, 0.f, 0.f};
  #pragma unroll
  for (int d = 0; d < 4; d++) oacc[d] = zero;
  #pragma unroll
  for (int j = 0; j < 4; j++) { mrow[j] = -1e30f; lrow[j] = 0.0f; }

  short8 vv[2];
  // ---- prologue: stage tile kt=0 into buf 0
  #pragma unroll
  for (int c = 0; c < 2; c++) {
    int ci = (wid * 2 + c) * 64 + lane;
    int row = ci >> 3;
    int lch = (ci & 7) ^ (row & 7);
    GLD_LDS16(Kb + base + (size_t)(row)*64 + lch * 8, (u16*)Ks[0] + (wid * 2 + c) * 512);
  }
  #pragma unroll
  for (int c = 0; c < 2; c++)
    vv[c] = *(const short8*)&Vb[base + (size_t)lane * 64 + (c * 4 + wid) * 8];
  asm volatile("s_waitcnt vmcnt(0)" ::: "memory");
  #pragma unroll
  for (int c = 0; c < 2; c++)
    #pragma unroll
    for (int j = 0; j < 8; j++) {
      int d = (c * 4 + wid) * 8 + j;
      int byt = d * 128 + (((lane >> 3) ^ (d & 7)) << 4) + ((lane & 7) << 1);
      *(u16*)((char*)Vt[0] + byt) = (u16)vv[c][j];
    }
  __syncthreads();

  int buf = 0;
  for (int kt = 0; kt <= qt; kt++) {
    // ---- prefetch next tile (issue early)
    if (kt < qt) {
      #pragma unroll
      for (int c = 0; c < 2; c++) {
        int ci = (wid * 2 + c) * 64 + lane;
        int row = ci >> 3;
        int lch = (ci & 7) ^ (row & 7);
        GLD_LDS16(Kb + base + (size_t)((kt + 1) * 64 + row) * 64 + lch * 8,
                  (u16*)Ks[buf ^ 1] + (wid * 2 + c) * 512);
      }
      #pragma unroll
      for (int c = 0; c < 2; c++)
        vv[c] = *(const short8*)&Vb[base + (size_t)((kt + 1) * 64 + lane) * 64
                                    + (c * 4 + wid) * 8];
    }

    // ---- S = (Q K^T) / 8, causal mask on diagonal tile
    f32x4 sv[4];
    #pragma unroll
    for (int nt = 0; nt < 4; nt++) {
      f32x4 s = zero;
      #pragma unroll
      for (int kc = 0; kc < 2; kc++) {
        int row = nt * 16 + lr;
        int pch = (kc * 4 + lg) ^ (row & 7);
        short8 kf = *(const short8*)((const char*)Ks[buf] + row * 128 + pch * 16);
        s = __builtin_amdgcn_mfma_f32_16x16x32_bf16(qf[kc], kf, s, 0, 0, 0);
      }
      s *= 0.125f;
      if (kt == qt) {
        int key = kt * 64 + nt * 16 + lr;
        #pragma unroll
        for (int j = 0; j < 4; j++) {
          int q = qt * 64 + wid * 16 + lg * 4 + j;
          if (key > q) s[j] = -1e30f;
        }
      }
      sv[nt] = s;
    }

    // ---- online softmax
    #pragma unroll
    for (int j = 0; j < 4; j++) {
      float tm = fmaxf(fmaxf(sv[0][j], sv[1][j]), fmaxf(sv[2][j], sv[3][j]));
      #pragma unroll
      for (int off = 8; off >= 1; off >>= 1) tm = fmaxf(tm, __shfl_xor(tm, off, 64));
      float mnew = fmaxf(mrow[j], tm);
      float esc = __expf(mrow[j] - mnew);
      mrow[j] = mnew;
      float rs = 0.f;
      #pragma unroll
      for (int nt = 0; nt < 4; nt++) {
        float p = __expf(sv[nt][j] - mnew);
        sv[nt][j] = p;
        rs += p;
      }
      #pragma unroll
      for (int off = 8; off >= 1; off >>= 1) rs += __shfl_xor(rs, off, 64);
      lrow[j] = lrow[j] * esc + rs;
      #pragma unroll
      for (int dt = 0; dt < 4; dt++) oacc[dt][j] *= esc;
    }

    // ---- P (C layout) -> per-wave LDS -> A frags
    u16* myP = (u16*)Ps + wid * (16 * 72);
    #pragma unroll
    for (int nt = 0; nt < 4; nt++)
      #pragma unroll
      for (int j = 0; j < 4; j++)
        myP[(lg * 4 + j) * 72 + nt * 16 + lr] = f2bf(sv[nt][j]);
    asm volatile("s_waitcnt lgkmcnt(0)" ::: "memory");
    short8 pa[2];
    #pragma unroll
    for (int kc = 0; kc < 2; kc++)
      pa[kc] = *(const short8*)&myP[lr * 72 + kc * 32 + lg * 8];

    // ---- O += P V
    #pragma unroll
    for (int dt = 0; dt < 4; dt++) {
      #pragma unroll
      for (int kc = 0; kc < 2; kc++) {
        int d = dt * 16 + lr;
        int pch = (kc * 4 + lg) ^ (d & 7);
        short8 vf = *(const short8*)((const char*)Vt[buf] + d * 128 + pch * 16);
        oacc[dt] = __builtin_amdgcn_mfma_f32_16x16x32_bf16(pa[kc], vf, oacc[dt], 0, 0, 0);
      }
    }

    // ---- finish prefetch: drain loads, write V regs to next buffer
    if (kt < qt) {
      asm volatile("s_waitcnt vmcnt(0)" ::: "memory");
      #pragma unroll
      for (int c = 0; c < 2; c++)
        #pragma unroll
        for (int j = 0; j < 8; j++) {
          int d = (c * 4 + wid) * 8 + j;
          int byt = d * 128 + (((lane >> 3) ^ (d & 7)) << 4) + ((lane & 7) << 1);
          *(u16*)((char*)Vt[buf ^ 1] + byt) = (u16)vv[c][j];
        }
    }
    __syncthreads();
    buf ^= 1;
  }

  // write O as (B,S,D) bf16
  const int b = bh >> 4, h = bh & 15;
  #pragma unroll
  for (int dt = 0; dt < 4; dt++)
    #pragma unroll
    for (int j = 0; j < 4; j++) {
      int sq = qt * 64 + wid * 16 + lg * 4 + j;
      Ob[((size_t)(b * 2048 + sq)) * 1024 + h * 64 + dt * 16 + lr] =
          f2bf(oacc[dt][j] / lrow[j]);
    }
}

// ---------------- launch ----------------------------------------------------
extern "C" void kernel_launch(void* const* d_in, const int* in_sizes, int n_in,
                              void* d_out, int out_size, void* d_ws, size_t ws_size,
                              hipStream_t stream)
{
  const float* x  = (const float*)d_in[0];
  const float* wq = (const float*)d_in[1];
  const float* wk = (const float*)d_in[2];
  const float* wv = (const float*)d_in[3];
  const float* wo = (const float*)d_in[4];
  const float* w1 = (const float*)d_in[5];
  const float* w2 = (const float*)d_in[6];
  const float* w3 = (const float*)d_in[7];
  const float* g1 = (const float*)d_in[8];
  const float* g2 = (const float*)d_in[9];
  float* out = (float*)d_out;
  char* ws = (char*)d_ws;

  u16*    wqb  = (u16*)   (ws + 0 * MBYTE);
  u16*    wkb  = (u16*)   (ws + 2 * MBYTE);
  u16*    wvb  = (u16*)   (ws + 4 * MBYTE);
  u16*    wob  = (u16*)   (ws + 6 * MBYTE);
  u16*    w1b  = (u16*)   (ws + 8 * MBYTE);
  u16*    w2b  = (u16*)   (ws + 16 * MBYTE);
  u16*    w3b  = (u16*)   (ws + 24 * MBYTE);
  float2* trig = (float2*)(ws + 32 * MBYTE);
  float*  x2   = (float*) (ws + 33 * MBYTE);
  u16*    hb   = (u16*)   (ws + 49 * MBYTE);
  u16*    Qb   = (u16*)   (ws + 57 * MBYTE);
  u16*    Kb   = (u16*)   (ws + 65 * MBYTE);
  u16*    Vb   = (u16*)   (ws + 73 * MBYTE);
  u16*    Ob   = (u16*)   (ws + 81 * MBYTE);
  u16*    f1   = (u16*)   (ws + 57 * MBYTE);   // reuse Q..O after attention

  prep_kernel<<<dim3(4096, 8), 256, 0, stream>>>(wq, wk, wv, wo, w1, w2, w3,
                                                 wqb, wkb, wvb, wob, w1b, w2b, w3b,
                                                 trig);
  rmsnorm_kernel<<<4096, 256, 0, stream>>>(x, g1, hb);
  gemm_qkv<<<dim3(8, 32, 3), 256, 0, stream>>>(hb, wqb, wkb, wvb, Qb, Kb, Vb, trig);
  flash_attn<<<dim3(32, 32), 256, 0, stream>>>(Qb, Kb, Vb, Ob);
  gemm_one<2, 64, 128, 1, 4><<<dim3(8, 64), 256, 0, stream>>>(
      Ob, wob, 1024, 1024, nullptr, x2, x);
  rmsnorm_kernel<<<4096, 256, 0, stream>>>(x2, g2, hb);
  gemm_ffn13<<<dim3(64, 32), 256, 0, stream>>>(hb, w1b, w3b, f1);
  gemm_one<2, 64, 128, 1, 4><<<dim3(8, 64), 256, 0, stream>>>(
      f1, w2b, 4096, 1024, nullptr, out, x2);
}

// Round 10
// 483.749 us; speedup vs baseline: 1.1849x; 1.0290x over previous
//
#include <hip/hip_runtime.h>

// TransformerBlock: B=2, S=2048, D=1024, F=4096, H=16, Dh=64, M=B*S=4096.
// Mixed precision: bf16 MFMA GEMMs + flash attention, fp32 norms/softmax/residuals.
// R9: flash_attn pairs q-tiles (p, 31-p) in one block -> uniform 33 phases/block,
//     shared K/V staging, grid 512 = exactly 2 blocks/CU. Rest unchanged.

typedef unsigned short u16;
typedef __attribute__((ext_vector_type(8))) short short8;   // 8 x bf16 MFMA frag
typedef __attribute__((ext_vector_type(4))) float f32x4;    // MFMA acc

#define MBYTE ((size_t)1 << 20)

typedef void __attribute__((address_space(3))) lds_void;
typedef void __attribute__((address_space(1))) glb_void;
#define GLD_LDS16(gp, lp) \
  __builtin_amdgcn_global_load_lds((glb_void*)(gp), (lds_void*)(lp), 16, 0, 0)

__device__ __forceinline__ u16 f2bf(float f) {              // RNE f32 -> bf16
  union { float f; unsigned u; } v; v.f = f;
  unsigned r = v.u + 0x7FFFu + ((v.u >> 16) & 1u);
  return (u16)(r >> 16);
}
__device__ __forceinline__ float bf2f(u16 h) {
  union { unsigned u; float f; } v; v.u = ((unsigned)h) << 16;
  return v.f;
}

// ---------------- weight convert + RoPE table ----------------
__global__ __launch_bounds__(256)
void prep_kernel(const float* __restrict__ wq, const float* __restrict__ wk,
                 const float* __restrict__ wv, const float* __restrict__ wo,
                 const float* __restrict__ w1, const float* __restrict__ w2,
                 const float* __restrict__ w3,
                 u16* wqb, u16* wkb, u16* wvb, u16* wob,
                 u16* w1b, u16* w2b, u16* w3b, float2* trig)
{
  const int y = blockIdx.y;
  if (y == 7) {                                   // cos/sin table [S=2048][32]
    const int idx = blockIdx.x * 256 + threadIdx.x;
    if (idx < 2048 * 32) {
      const int s = idx >> 5, i = idx & 31;
      const float inv = powf(10000.0f, -(float)(2 * i) / 64.0f);
      const float ang = (float)s * inv;
      trig[idx] = make_float2(cosf(ang), sinf(ang));
    }
    return;
  }
  const float* src; u16* dst; int n;
  switch (y) {
    case 0: src = wq; dst = wqb; n = 1 << 20; break;
    case 1: src = wk; dst = wkb; n = 1 << 20; break;
    case 2: src = wv; dst = wvb; n = 1 << 20; break;
    case 3: src = wo; dst = wob; n = 1 << 20; break;
    case 4: src = w1; dst = w1b; n = 1 << 22; break;
    case 5: src = w2; dst = w2b; n = 1 << 22; break;
    default: src = w3; dst = w3b; n = 1 << 22; break;
  }
  const int idx = (blockIdx.x * 256 + threadIdx.x) * 4;
  if (idx >= n) return;
  const float4 v = *(const float4*)(src + idx);
  ushort4 o; o.x = f2bf(v.x); o.y = f2bf(v.y); o.z = f2bf(v.z); o.w = f2bf(v.w);
  *(ushort4*)(dst + idx) = o;
}

// ---------------- RMSNorm: fp32 in -> bf16 out, one row per block ----------
__global__ __launch_bounds__(256)
void rmsnorm_kernel(const float* __restrict__ x, const float* __restrict__ g,
                    u16* __restrict__ out)
{
  __shared__ float red[4];
  const int row = blockIdx.x, tid = threadIdx.x;
  const float4 v = ((const float4*)(x + (size_t)row * 1024))[tid];
  float ss = v.x * v.x + v.y * v.y + v.z * v.z + v.w * v.w;
  #pragma unroll
  for (int off = 32; off >= 1; off >>= 1) ss += __shfl_xor(ss, off, 64);
  if ((tid & 63) == 0) red[tid >> 6] = ss;
  __syncthreads();
  const float tot = red[0] + red[1] + red[2] + red[3];
  const float rs = rsqrtf(tot * (1.0f / 1024.0f) + 1e-5f);
  const float4 gg = ((const float4*)g)[tid];
  ushort4 o;
  o.x = f2bf(v.x * rs * gg.x); o.y = f2bf(v.y * rs * gg.y);
  o.z = f2bf(v.z * rs * gg.z); o.w = f2bf(v.w * rs * gg.w);
  ((ushort4*)(out + (size_t)row * 1024))[tid] = o;
}

// ---------------- GEMM core (m97 structure): C = A(MxK) * W(NxK)^T ---------
template<int TM, int TN, int WRN, int WCN>
__device__ __forceinline__ void gemm_core(const u16* __restrict__ A,
                                          const u16* __restrict__ Bw,
                                          int K, int bm, int bn,
                                          u16* As, u16* Bs,
                                          f32x4 (&acc)[TM / (16 * WRN)][TN / (16 * WCN)])
{
  constexpr int MT = TM / (16 * WRN), NT = TN / (16 * WCN);
  constexpr int CA = TM / 16, CB = TN / 16;    // 1KB staging chunks
  const int tid = threadIdx.x, wid = tid >> 6, lane = tid & 63;
  const int wr = wid / WCN, wc = wid % WCN;
  const int lr = lane & 15, lg = lane >> 4;
  const int srow = lane >> 2;                  // row within 16-row chunk
  const int skel = (lane & 3) * 8;             // k-element offset (8 bf16 = 16B)
  const size_t aRow0 = (size_t)bm * TM;
  const size_t bRow0 = (size_t)bn * TN;

  for (int k0 = 0; k0 < K; k0 += 32) {
    #pragma unroll
    for (int i = 0; i < CA / 4; i++) {
      int c = wid + i * 4;
      GLD_LDS16(A + (aRow0 + c * 16 + srow) * K + k0 + skel, As + c * 512);
    }
    #pragma unroll
    for (int i = 0; i < CB / 4; i++) {
      int c = wid + i * 4;
      GLD_LDS16(Bw + (bRow0 + c * 16 + srow) * K + k0 + skel, Bs + c * 512);
    }
    __syncthreads();
    short8 af[MT], bfr[NT];
    #pragma unroll
    for (int mt = 0; mt < MT; mt++)
      af[mt] = *(const short8*)&As[(wr * (MT * 16) + mt * 16 + lr) * 32 + lg * 8];
    #pragma unroll
    for (int nt = 0; nt < NT; nt++)
      bfr[nt] = *(const short8*)&Bs[(wc * (NT * 16) + nt * 16 + lr) * 32 + lg * 8];
    #pragma unroll
    for (int mt = 0; mt < MT; mt++)
      #pragma unroll
      for (int nt = 0; nt < NT; nt++)
        acc[mt][nt] = __builtin_amdgcn_mfma_f32_16x16x32_bf16(af[mt], bfr[nt],
                                                              acc[mt][nt], 0, 0, 0);
    __syncthreads();
  }
}

// ---- QKV GEMM: z picks weight; RoPE fused in epilogue; (B,H,S,Dh) store ----
__global__ __launch_bounds__(256)
void gemm_qkv(const u16* __restrict__ A,
              const u16* __restrict__ wqb, const u16* __restrict__ wkb,
              const u16* __restrict__ wvb,
              u16* Qb, u16* Kb, u16* Vb, const float2* __restrict__ trig)
{
  __shared__ u16 As[128 * 32];
  __shared__ u16 Bs[128 * 32];
  const u16* Bw = blockIdx.z == 0 ? wqb : (blockIdx.z == 1 ? wkb : wvb);
  u16* out = blockIdx.z == 0 ? Qb : (blockIdx.z == 1 ? Kb : Vb);
  const bool isQK = blockIdx.z < 2;
  f32x4 acc[4][4];
  const f32x4 zero = {0.f, 0.f, 0.f, 0.f};
  #pragma unroll
  for (int i = 0; i < 4; i++)
    #pragma unroll
    for (int j = 0; j < 4; j++) acc[i][j] = zero;
  gemm_core<128, 128, 2, 2>(A, Bw, 1024, blockIdx.y, blockIdx.x, As, Bs, acc);
  const int lane = threadIdx.x & 63, wid = threadIdx.x >> 6;
  const int wr = wid >> 1, wc = wid & 1, lr = lane & 15, lg = lane >> 4;
  #pragma unroll
  for (int mt = 0; mt < 4; mt++)
    #pragma unroll
    for (int nt = 0; nt < 4; nt++)
      #pragma unroll
      for (int j = 0; j < 4; j++) {
        int row = blockIdx.y * 128 + wr * 64 + mt * 16 + lg * 4 + j;  // m = b*2048+s
        int col = blockIdx.x * 128 + wc * 64 + nt * 16 + lr;          // n = h*64+d
        int b = row >> 11, s = row & 2047, hh = col >> 6, d = col & 63;
        float v = acc[mt][nt][j];
        if (isQK) {
          // RoPE pair (2i,2i+1) sits on lanes lr, lr^1 (same lg) of this tile.
          float p = __shfl_xor(v, 1);
          const float2 cs = trig[s * 32 + (d >> 1)];
          v = ((d & 1) == 0) ? (v * cs.x - p * cs.y)   // r1 = x1*cos - x2*sin
                             : (p * cs.y + v * cs.x);  // r2 = x1*sin + x2*cos
        }
        out[(((size_t)(b * 16 + hh)) * 2048 + s) * 64 + d] = f2bf(v);
      }
}

// ---------------- generic GEMM with epilogue variants -----------------------
// EP: 1 = bf16 store; 2 = fp32 store of res+acc
template<int EP, int TM, int TN, int WRN, int WCN>
__global__ __launch_bounds__(256)
void gemm_one(const u16* __restrict__ A, const u16* __restrict__ Bw, int K, int N,
              u16* outb, float* outf, const float* res)
{
  __shared__ u16 As[TM * 32];
  __shared__ u16 Bs[TN * 32];
  constexpr int MT = TM / (16 * WRN), NT = TN / (16 * WCN);
  f32x4 acc[MT][NT];
  const f32x4 zero = {0.f, 0.f, 0.f, 0.f};
  #pragma unroll
  for (int i = 0; i < MT; i++)
    #pragma unroll
    for (int j = 0; j < NT; j++) acc[i][j] = zero;
  gemm_core<TM, TN, WRN, WCN>(A, Bw, K, blockIdx.y, blockIdx.x, As, Bs, acc);
  const int lane = threadIdx.x & 63, wid = threadIdx.x >> 6;
  const int wr = wid / WCN, wc = wid % WCN, lr = lane & 15, lg = lane >> 4;
  #pragma unroll
  for (int mt = 0; mt < MT; mt++)
    #pragma unroll
    for (int nt = 0; nt < NT; nt++)
      #pragma unroll
      for (int j = 0; j < 4; j++) {
        int row = blockIdx.y * TM + wr * (MT * 16) + mt * 16 + lg * 4 + j;
        int col = blockIdx.x * TN + wc * (NT * 16) + nt * 16 + lr;
        size_t o = (size_t)row * N + col;
        float v = acc[mt][nt][j];
        if constexpr (EP == 1) {
          outb[o] = f2bf(v);
        } else {
          outf[o] = res[o] + v;
        }
      }
}

// ---- fused FFN up: f1 = silu(h w1^T) * (h w3^T), bf16 out ------------------
// TM=128, TN=64, 4 waves (2x2), A staged once for both weights.
__global__ __launch_bounds__(256)
void gemm_ffn13(const u16* __restrict__ A, const u16* __restrict__ W1,
                const u16* __restrict__ W3, u16* __restrict__ outb)
{
  __shared__ u16 As[128 * 32];
  __shared__ u16 B1s[64 * 32];
  __shared__ u16 B3s[64 * 32];
  f32x4 acc1[4][2], acc3[4][2];
  const f32x4 zero = {0.f, 0.f, 0.f, 0.f};
  #pragma unroll
  for (int i = 0; i < 4; i++)
    #pragma unroll
    for (int j = 0; j < 2; j++) { acc1[i][j] = zero; acc3[i][j] = zero; }
  const int tid = threadIdx.x, wid = tid >> 6, lane = tid & 63;
  const int wr = wid >> 1, wc = wid & 1;
  const int lr = lane & 15, lg = lane >> 4;
  const int srow = lane >> 2;
  const int skel = (lane & 3) * 8;
  const size_t aRow0 = (size_t)blockIdx.y * 128;
  const size_t bRow0 = (size_t)blockIdx.x * 64;

  for (int k0 = 0; k0 < 1024; k0 += 32) {
    #pragma unroll
    for (int i = 0; i < 2; i++) {
      int c = wid + i * 4;
      GLD_LDS16(A + (aRow0 + c * 16 + srow) * 1024 + k0 + skel, As + c * 512);
    }
    GLD_LDS16(W1 + (bRow0 + wid * 16 + srow) * 1024 + k0 + skel, B1s + wid * 512);
    GLD_LDS16(W3 + (bRow0 + wid * 16 + srow) * 1024 + k0 + skel, B3s + wid * 512);
    __syncthreads();
    short8 af[4], b1[2], b3[2];
    #pragma unroll
    for (int mt = 0; mt < 4; mt++)
      af[mt] = *(const short8*)&As[(wr * 64 + mt * 16 + lr) * 32 + lg * 8];
    #pragma unroll
    for (int nt = 0; nt < 2; nt++) {
      b1[nt] = *(const short8*)&B1s[(wc * 32 + nt * 16 + lr) * 32 + lg * 8];
      b3[nt] = *(const short8*)&B3s[(wc * 32 + nt * 16 + lr) * 32 + lg * 8];
    }
    #pragma unroll
    for (int mt = 0; mt < 4; mt++)
      #pragma unroll
      for (int nt = 0; nt < 2; nt++) {
        acc1[mt][nt] = __builtin_amdgcn_mfma_f32_16x16x32_bf16(af[mt], b1[nt],
                                                               acc1[mt][nt], 0, 0, 0);
        acc3[mt][nt] = __builtin_amdgcn_mfma_f32_16x16x32_bf16(af[mt], b3[nt],
                                                               acc3[mt][nt], 0, 0, 0);
      }
    __syncthreads();
  }
  #pragma unroll
  for (int mt = 0; mt < 4; mt++)
    #pragma unroll
    for (int nt = 0; nt < 2; nt++)
      #pragma unroll
      for (int j = 0; j < 4; j++) {
        int row = blockIdx.y * 128 + wr * 64 + mt * 16 + lg * 4 + j;
        int col = blockIdx.x * 64 + wc * 32 + nt * 16 + lr;
        float v1 = acc1[mt][nt][j], v3 = acc3[mt][nt][j];
        float sg = v1 / (1.0f + __expf(-v1));
        outb[(size_t)row * 4096 + col] = f2bf(sg * v3);
      }
}

// ---------------- causal flash attention (v3: paired q-tiles) ---------------
// grid (16, 32): block p handles q-tiles {p, 31-p} for head bh.
// Uniform cost: (p+1) + (32-p) = 33 compute phases per block; K/V staged once
// for the union k-range 0..31-p. 512 blocks = exactly 2/CU, zero tail.
__global__ __launch_bounds__(256)
void flash_attn(const u16* __restrict__ Qb, const u16* __restrict__ Kb,
                const u16* __restrict__ Vb, u16* __restrict__ Ob)
{
  __shared__ u16 Ks[2][64 * 64];
  __shared__ u16 Vt[2][64 * 64];
  __shared__ u16 Ps[4 * 16 * 72];
  const int tid = threadIdx.x, wid = tid >> 6, lane = tid & 63;
  const int lr = lane & 15, lg = lane >> 4;
  const int bh = blockIdx.y;
  const int qtA = blockIdx.x;          // 0..15
  const int qtB = 31 - qtA;            // 16..31  (qtA < qtB always)
  const size_t base = (size_t)bh * (2048 * 64);
  const f32x4 zero = {0.f, 0.f, 0.f, 0.f};

  short8 qfA[2], qfB[2];
  #pragma unroll
  for (int kc = 0; kc < 2; kc++) {
    qfA[kc] = *(const short8*)&Qb[base + (size_t)(qtA * 64 + wid * 16 + lr) * 64
                                  + kc * 32 + lg * 8];
    qfB[kc] = *(const short8*)&Qb[base + (size_t)(qtB * 64 + wid * 16 + lr) * 64
                                  + kc * 32 + lg * 8];
  }

  f32x4 oaccA[4], oaccB[4];
  float mrowA[4], lrowA[4], mrowB[4], lrowB[4];
  #pragma unroll
  for (int d = 0; d < 4; d++) { oaccA[d] = zero; oaccB[d] = zero; }
  #pragma unroll
  for (int j = 0; j < 4; j++) {
    mrowA[j] = -1e30f; lrowA[j] = 0.0f;
    mrowB[j] = -1e30f; lrowB[j] = 0.0f;
  }

  // one q-tile's inner phase: QK -> online softmax -> P roundtrip -> PV
  auto process = [&](int kt, int qtX, const short8 (&qf)[2], f32x4 (&oacc)[4],
                     float (&mrow)[4], float (&lrow)[4], int buf) {
    f32x4 sv[4];
    #pragma unroll
    for (int nt = 0; nt < 4; nt++) {
      f32x4 s = zero;
      #pragma unroll
      for (int kc = 0; kc < 2; kc++) {
        int row = nt * 16 + lr;
        int pch = (kc * 4 + lg) ^ (row & 7);
        short8 kf = *(const short8*)((const char*)Ks[buf] + row * 128 + pch * 16);
        s = __builtin_amdgcn_mfma_f32_16x16x32_bf16(qf[kc], kf, s, 0, 0, 0);
      }
      s *= 0.125f;
      if (kt == qtX) {
        int key = kt * 64 + nt * 16 + lr;
        #pragma unroll
        for (int j = 0; j < 4; j++) {
          int q = qtX * 64 + wid * 16 + lg * 4 + j;
          if (key > q) s[j] = -1e30f;
        }
      }
      sv[nt] = s;
    }

    #pragma unroll
    for (int j = 0; j < 4; j++) {
      float tm = fmaxf(fmaxf(sv[0][j], sv[1][j]), fmaxf(sv[2][j], sv[3][j]));
      #pragma unroll
      for (int off = 8; off >= 1; off >>= 1) tm = fmaxf(tm, __shfl_xor(tm, off, 64));
      float mnew = fmaxf(mrow[j], tm);
      float esc = __expf(mrow[j] - mnew);
      mrow[j] = mnew;
      float rs = 0.f;
      #pragma unroll
      for (int nt = 0; nt < 4; nt++) {
        float p = __expf(sv[nt][j] - mnew);
        sv[nt][j] = p;
        rs += p;
      }
      #pragma unroll
      for (int off = 8; off >= 1; off >>= 1) rs += __shfl_xor(rs, off, 64);
      lrow[j] = lrow[j] * esc + rs;
      #pragma unroll
      for (int dt = 0; dt < 4; dt++) oacc[dt][j] *= esc;
    }

    u16* myP = (u16*)Ps + wid * (16 * 72);
    #pragma unroll
    for (int nt = 0; nt < 4; nt++)
      #pragma unroll
      for (int j = 0; j < 4; j++)
        myP[(lg * 4 + j) * 72 + nt * 16 + lr] = f2bf(sv[nt][j]);
    asm volatile("s_waitcnt lgkmcnt(0)" ::: "memory");
    short8 pa[2];
    #pragma unroll
    for (int kc = 0; kc < 2; kc++)
      pa[kc] = *(const short8*)&myP[lr * 72 + kc * 32 + lg * 8];

    #pragma unroll
    for (int dt = 0; dt < 4; dt++) {
      #pragma unroll
      for (int kc = 0; kc < 2; kc++) {
        int d = dt * 16 + lr;
        int pch = (kc * 4 + lg) ^ (d & 7);
        short8 vf = *(const short8*)((const char*)Vt[buf] + d * 128 + pch * 16);
        oacc[dt] = __builtin_amdgcn_mfma_f32_16x16x32_bf16(pa[kc], vf, oacc[dt], 0, 0, 0);
      }
    }
  };

  short8 vv[2];
  // ---- prologue: stage tile kt=0 into buf 0
  #pragma unroll
  for (int c = 0; c < 2; c++) {
    int ci = (wid * 2 + c) * 64 + lane;
    int row = ci >> 3;
    int lch = (ci & 7) ^ (row & 7);
    GLD_LDS16(Kb + base + (size_t)(row)*64 + lch * 8, (u16*)Ks[0] + (wid * 2 + c) * 512);
  }
  #pragma unroll
  for (int c = 0; c < 2; c++)
    vv[c] = *(const short8*)&Vb[base + (size_t)lane * 64 + (c * 4 + wid) * 8];
  asm volatile("s_waitcnt vmcnt(0)" ::: "memory");
  #pragma unroll
  for (int c = 0; c < 2; c++)
    #pragma unroll
    for (int j = 0; j < 8; j++) {
      int d = (c * 4 + wid) * 8 + j;
      int byt = d * 128 + (((lane >> 3) ^ (d & 7)) << 4) + ((lane & 7) << 1);
      *(u16*)((char*)Vt[0] + byt) = (u16)vv[c][j];
    }
  __syncthreads();

  int buf = 0;
  for (int kt = 0; kt <= qtB; kt++) {
    // ---- prefetch next tile (issue early)
    if (kt < qtB) {
      #pragma unroll
      for (int c = 0; c < 2; c++) {
        int ci = (wid * 2 + c) * 64 + lane;
        int row = ci >> 3;
        int lch = (ci & 7) ^ (row & 7);
        GLD_LDS16(Kb + base + (size_t)((kt + 1) * 64 + row) * 64 + lch * 8,
                  (u16*)Ks[buf ^ 1] + (wid * 2 + c) * 512);
      }
      #pragma unroll
      for (int c = 0; c < 2; c++)
        vv[c] = *(const short8*)&Vb[base + (size_t)((kt + 1) * 64 + lane) * 64
                                    + (c * 4 + wid) * 8];
    }

    // ---- tile A (only while kt within its causal range), then tile B
    if (kt <= qtA)
      process(kt, qtA, qfA, oaccA, mrowA, lrowA, buf);
    process(kt, qtB, qfB, oaccB, mrowB, lrowB, buf);

    // ---- finish prefetch: drain loads, write V regs to next buffer
    if (kt < qtB) {
      asm volatile("s_waitcnt vmcnt(0)" ::: "memory");
      #pragma unroll
      for (int c = 0; c < 2; c++)
        #pragma unroll
        for (int j = 0; j < 8; j++) {
          int d = (c * 4 + wid) * 8 + j;
          int byt = d * 128 + (((lane >> 3) ^ (d & 7)) << 4) + ((lane & 7) << 1);
          *(u16*)((char*)Vt[buf ^ 1] + byt) = (u16)vv[c][j];
        }
    }
    __syncthreads();
    buf ^= 1;
  }

  // ---- write both O tiles as (B,S,D) bf16
  const int b = bh >> 4, h = bh & 15;
  #pragma unroll
  for (int dt = 0; dt < 4; dt++)
    #pragma unroll
    for (int j = 0; j < 4; j++) {
      int sqA = qtA * 64 + wid * 16 + lg * 4 + j;
      int sqB = qtB * 64 + wid * 16 + lg * 4 + j;
      Ob[((size_t)(b * 2048 + sqA)) * 1024 + h * 64 + dt * 16 + lr] =
          f2bf(oaccA[dt][j] / lrowA[j]);
      Ob[((size_t)(b * 2048 + sqB)) * 1024 + h * 64 + dt * 16 + lr] =
          f2bf(oaccB[dt][j] / lrowB[j]);
    }
}

// ---------------- launch ----------------------------------------------------
extern "C" void kernel_launch(void* const* d_in, const int* in_sizes, int n_in,
                              void* d_out, int out_size, void* d_ws, size_t ws_size,
                              hipStream_t stream)
{
  const float* x  = (const float*)d_in[0];
  const float* wq = (const float*)d_in[1];
  const float* wk = (const float*)d_in[2];
  const float* wv = (const float*)d_in[3];
  const float* wo = (const float*)d_in[4];
  const float* w1 = (const float*)d_in[5];
  const float* w2 = (const float*)d_in[6];
  const float* w3 = (const float*)d_in[7];
  const float* g1 = (const float*)d_in[8];
  const float* g2 = (const float*)d_in[9];
  float* out = (float*)d_out;
  char* ws = (char*)d_ws;

  u16*    wqb  = (u16*)   (ws + 0 * MBYTE);
  u16*    wkb  = (u16*)   (ws + 2 * MBYTE);
  u16*    wvb  = (u16*)   (ws + 4 * MBYTE);
  u16*    wob  = (u16*)   (ws + 6 * MBYTE);
  u16*    w1b  = (u16*)   (ws + 8 * MBYTE);
  u16*    w2b  = (u16*)   (ws + 16 * MBYTE);
  u16*    w3b  = (u16*)   (ws + 24 * MBYTE);
  float2* trig = (float2*)(ws + 32 * MBYTE);
  float*  x2   = (float*) (ws + 33 * MBYTE);
  u16*    hb   = (u16*)   (ws + 49 * MBYTE);
  u16*    Qb   = (u16*)   (ws + 57 * MBYTE);
  u16*    Kb   = (u16*)   (ws + 65 * MBYTE);
  u16*    Vb   = (u16*)   (ws + 73 * MBYTE);
  u16*    Ob   = (u16*)   (ws + 81 * MBYTE);
  u16*    f1   = (u16*)   (ws + 57 * MBYTE);   // reuse Q..O after attention

  prep_kernel<<<dim3(4096, 8), 256, 0, stream>>>(wq, wk, wv, wo, w1, w2, w3,
                                                 wqb, wkb, wvb, wob, w1b, w2b, w3b,
                                                 trig);
  rmsnorm_kernel<<<4096, 256, 0, stream>>>(x, g1, hb);
  gemm_qkv<<<dim3(8, 32, 3), 256, 0, stream>>>(hb, wqb, wkb, wvb, Qb, Kb, Vb, trig);
  flash_attn<<<dim3(16, 32), 256, 0, stream>>>(Qb, Kb, Vb, Ob);
  gemm_one<2, 64, 128, 1, 4><<<dim3(8, 64), 256, 0, stream>>>(
      Ob, wob, 1024, 1024, nullptr, x2, x);
  rmsnorm_kernel<<<4096, 256, 0, stream>>>(x2, g2, hb);
  gemm_ffn13<<<dim3(64, 32), 256, 0, stream>>>(hb, w1b, w3b, f1);
  gemm_one<2, 64, 128, 1, 4><<<dim3(8, 64), 256, 0, stream>>>(
      f1, w2b, 4096, 1024, nullptr, out, x2);
}